// Round 6
// baseline (172.276 us; speedup 1.0000x reference)
//
#include <hip/hip_runtime.h>
#include <math.h>

#define LEN 4096
#define NSTATE 64

__device__ inline float2 cmulf(float2 a, float2 b){
  return make_float2(a.x*b.x - a.y*b.y, a.x*b.y + a.y*b.x);
}
// a * conj(b)
__device__ inline float2 cmulcf(float2 a, float2 b){
  return make_float2(a.x*b.x + a.y*b.y, a.y*b.x - a.x*b.y);
}
__device__ inline float2 cadd(float2 a, float2 b){ return make_float2(a.x+b.x, a.y+b.y); }
__device__ inline float2 csub(float2 a, float2 b){ return make_float2(a.x-b.x, a.y-b.y); }

// ---- 16-point DFT in registers, natural order in and out ----
template<bool INV>
__device__ inline void dft16(float2 v[16]) {
  const float C1 = 0.923879532511286756f;   // cos(pi/8)
  const float S1 = 0.382683432365089772f;   // sin(pi/8)
  const float R  = 0.707106781186547524f;   // sqrt(2)/2
  const float sg = INV ? 1.0f : -1.0f;
  const float2 W1 = make_float2( C1,  sg*S1);
  const float2 W2 = make_float2( R,   sg*R );
  const float2 W3 = make_float2( S1,  sg*C1);
  const float2 W6 = make_float2(-R,   sg*R );
  const float2 W9 = make_float2(-C1, -sg*S1);

#define BFLY4(a0,a1,a2,a3, o0,o1,o2,o3) { \
    float2 t0 = cadd(a0,a2), t1 = csub(a0,a2); \
    float2 t2 = cadd(a1,a3), t3 = csub(a1,a3); \
    o0 = cadd(t0,t2); o2 = csub(t0,t2); \
    if (!INV) { o1 = make_float2(t1.x + t3.y, t1.y - t3.x); \
                o3 = make_float2(t1.x - t3.y, t1.y + t3.x); } \
    else      { o1 = make_float2(t1.x - t3.y, t1.y + t3.x); \
                o3 = make_float2(t1.x + t3.y, t1.y - t3.x); } }

  float2 z[16];
  BFLY4(v[0], v[4], v[8],  v[12], z[0], z[4], z[8],  z[12]);
  { float2 y0,y1,y2,y3; BFLY4(v[1], v[5], v[9],  v[13], y0,y1,y2,y3);
    z[1]=y0; z[5]=cmulf(y1,W1); z[9] =cmulf(y2,W2); z[13]=cmulf(y3,W3); }
  { float2 y0,y1,y2,y3; BFLY4(v[2], v[6], v[10], v[14], y0,y1,y2,y3);
    z[2]=y0; z[6]=cmulf(y1,W2);
    z[10]= INV ? make_float2(-y2.y, y2.x) : make_float2(y2.y, -y2.x);  // *W16^4 = -+i
    z[14]=cmulf(y3,W6); }
  { float2 y0,y1,y2,y3; BFLY4(v[3], v[7], v[11], v[15], y0,y1,y2,y3);
    z[3]=y0; z[7]=cmulf(y1,W3); z[11]=cmulf(y2,W6); z[15]=cmulf(y3,W9); }
  float2 u[16];
  BFLY4(z[0], z[1], z[2], z[3],  u[0], u[1], u[2], u[3]);
  BFLY4(z[4], z[5], z[6], z[7],  u[4], u[5], u[6], u[7]);
  BFLY4(z[8], z[9], z[10],z[11], u[8], u[9], u[10],u[11]);
  BFLY4(z[12],z[13],z[14],z[15], u[12],u[13],u[14],u[15]);
  #pragma unroll
  for (int f = 0; f < 16; ++f) v[f] = u[((f & 3) << 2) | (f >> 2)];
#undef BFLY4
}

// apply twiddle table: v[k] *= tab[k] (k=0 entry is 1, multiplied anyway to stay branch-free)
__device__ inline void apply_tab(float2 v[16], const float4 w[8]) {
  #pragma unroll
  for (int j = 0; j < 8; ++j) {
    v[2*j]   = cmulf(v[2*j],   make_float2(w[j].x, w[j].y));
    v[2*j+1] = cmulf(v[2*j+1], make_float2(w[j].z, w[j].w));
  }
}
// apply conjugate of table (inverse rounds)
__device__ inline void apply_tab_conj(float2 v[16], const float4 w[8]) {
  #pragma unroll
  for (int j = 0; j < 8; ++j) {
    v[2*j]   = cmulcf(v[2*j],   make_float2(w[j].x, w[j].y));
    v[2*j+1] = cmulcf(v[2*j+1], make_float2(w[j].z, w[j].w));
  }
}

// ---------------- Setup kernel 1: K[k] via DPLR Cauchy sums (double precision) ----------------
__global__ __launch_bounds__(64)
void s4_kernelA1(const float* __restrict__ Lre, const float* __restrict__ Lim,
                 const float* __restrict__ Pre, const float* __restrict__ Pim,
                 const float* __restrict__ Bre, const float* __restrict__ Bim,
                 const float* __restrict__ Cre, const float* __restrict__ Cim,
                 float2* __restrict__ Kout) {
  const int k = blockIdx.x;
  const int n = threadIdx.x;   // 0..63

  double ang = -2.0 * M_PI * (double)k / (double)LEN;
  double orr = cos(ang), oi = sin(ang);
  double dr = 1.0 + orr, di = oi;
  double d2 = dr*dr + di*di;
  double nr = 1.0 - orr, ni = -oi;
  double inv_d2 = 1.0 / d2;
  double gr = 2000.0 * (nr*dr + ni*di) * inv_d2;   // g = (2/step)*(1-O)/(1+O)
  double gi = 2000.0 * (ni*dr - nr*di) * inv_d2;
  double cr = 2.0 * dr * inv_d2, ci = -2.0 * di * inv_d2;  // c = 2/(1+O)

  double lr = Lre[n], li = Lim[n];
  double pr = Pre[n], pi = Pim[n];
  double br = Bre[n], bi = Bim[n];
  double qr = Cre[n], qi = Cim[n];
  double er = gr - lr, ei = gi - li;
  double inv_e2 = 1.0 / (er*er + ei*ei);
  double den_r = er * inv_e2, den_i = -ei * inv_e2;   // 1/(g-Lambda)
  double cbr = qr*br + qi*bi, cbi = qr*bi - qi*br;    // conj(C)*B
  double cpr = qr*pr + qi*pi, cpi = qr*pi - qi*pr;    // conj(C)*P
  double pbr = pr*br + pi*bi, pbi = pr*bi - pi*br;    // conj(P)*B
  double ppr = pr*pr + pi*pi;                          // conj(P)*P (real)

  double k00r = den_r*cbr - den_i*cbi, k00i = den_r*cbi + den_i*cbr;
  double k01r = den_r*cpr - den_i*cpi, k01i = den_r*cpi + den_i*cpr;
  double k10r = den_r*pbr - den_i*pbi, k10i = den_r*pbi + den_i*pbr;
  double k11r = den_r*ppr,             k11i = den_i*ppr;

  #pragma unroll
  for (int off = 32; off >= 1; off >>= 1) {
    k00r += __shfl_xor(k00r, off); k00i += __shfl_xor(k00i, off);
    k01r += __shfl_xor(k01r, off); k01i += __shfl_xor(k01i, off);
    k10r += __shfl_xor(k10r, off); k10i += __shfl_xor(k10i, off);
    k11r += __shfl_xor(k11r, off); k11i += __shfl_xor(k11i, off);
  }

  if (n == 0) {
    double ar = 1.0 + k11r, ai = k11i;
    double inv_a2 = 1.0 / (ar*ar + ai*ai);
    double ivr = ar*inv_a2, ivi = -ai*inv_a2;
    double mr = k01r*k10r - k01i*k10i, mi = k01r*k10i + k01i*k10r;
    double tr = mr*ivr - mi*ivi, ti = mr*ivi + mi*ivr;
    double sr = k00r - tr, si = k00i - ti;
    double Kr = cr*sr - ci*si, Ki = cr*si + ci*sr;
    Kout[k] = make_float2((float)Kr, (float)Ki);
  }
}

// ---------------- Setup kernel 2: Hermitian-symmetrize, scale by 1/L, base-16 digit-reverse ----------------
__global__ void s4_kernelA2(const float2* __restrict__ Kin, float2* __restrict__ keff_br) {
  int p = blockIdx.x * blockDim.x + threadIdx.x;
  if (p >= LEN) return;
  int k = ((p & 15) << 8) | (p & 240) | (p >> 8);
  int kneg = (LEN - k) & (LEN - 1);
  float2 a = Kin[k], b = Kin[kneg];
  const float s = 0.5f / (float)LEN;   // Hermitian average + 1/L ifft normalization
  keff_br[p] = make_float2(s * (a.x + b.x), s * (a.y - b.y));
}

// ---------------- Setup kernel 3: twiddle tables (double precision, cast to float) ----------------
// tw4096[t*16+k] = exp(-2*pi*i*t*k/4096), t=0..255, k=0..15   (32 KB)
// tw256 [j*16+k] = exp(-2*pi*i*j*k/256),  j=0..15,  k=0..15   (2 KB)
__global__ void s4_kernelA3(float2* __restrict__ tw4096, float2* __restrict__ tw256) {
  int id = blockIdx.x * blockDim.x + threadIdx.x;   // 0..4095
  int t = id >> 4, k = id & 15;
  double ang = -2.0 * M_PI * (double)(t * k) / 4096.0;
  tw4096[id] = make_float2((float)cos(ang), (float)sin(ang));
  if (id < 256) {
    int j = id >> 4, k2 = id & 15;
    double a2 = -2.0 * M_PI * (double)(j * k2) / 256.0;
    tw256[id] = make_float2((float)cos(a2), (float)sin(a2));
  }
}

// ---------------- Main kernel: radix-16, 3 fwd + 3 inv rounds, 4 LDS round-trips ----------------
// LDS XOR swizzle (no padding -> 32768 B -> 5 blocks/CU); twiddles from L1/L2-resident tables.
#define PHYS(i) ((i) ^ (((i) >> 4) & 15))

__launch_bounds__(256)
__global__ void s4_fftconv(const float* __restrict__ x, const float2* __restrict__ keff_br,
                           const float4* __restrict__ tw4096, const float4* __restrict__ tw256,
                           float* __restrict__ out) {
  __shared__ float2 X[LEN];
  const int t = threadIdx.x;
  const size_t base = (size_t)blockIdx.x * 2 * LEN;
  const float* x1 = x + base;
  const float* x2 = x1 + LEN;

  // NOTE units: tables are float2[ ]; viewed as float4, thread t's 16 twiddles
  // start at float2-index 16*t == float4-index 8*t (was the round-5 bug: 4*t).
  const float4* twA = tw4096 + 8*t;          // 8 float4 = 16 twiddles (round 1/6)
  const float4* twB = tw256  + 8*(t & 15);   // round 2/5

  // prefetch keff (16 float2 = 8 float4) into registers
  float4 kk[8];
  { const float4* kp = (const float4*)(keff_br + 16*t);
    #pragma unroll
    for (int j = 0; j < 8; ++j) kk[j] = kp[j]; }

  float2 v[16];
  float4 w[8];

  // ---- fwd round 1 (n=4096, q=256, j=t), fused with global load ----
  #pragma unroll
  for (int j = 0; j < 8; ++j) w[j] = twA[j];
  #pragma unroll
  for (int k = 0; k < 16; ++k)
    v[k] = make_float2(x1[t + 256*k], x2[t + 256*k]);
  dft16<false>(v);
  apply_tab(v, w);
  #pragma unroll
  for (int k = 0; k < 16; ++k) { int i = t + 256*k; X[PHYS(i)] = v[k]; }
  __syncthreads();

  // ---- fwd round 2 (n=256, q=16, j=t&15) ----
  const int i0 = ((t >> 4) << 8) + (t & 15);
  #pragma unroll
  for (int j = 0; j < 8; ++j) w[j] = twB[j];
  #pragma unroll
  for (int k = 0; k < 16; ++k) { int i = i0 + 16*k; v[k] = X[PHYS(i)]; }
  dft16<false>(v);
  apply_tab(v, w);
  #pragma unroll
  for (int k = 0; k < 16; ++k) { int i = i0 + 16*k; X[PHYS(i)] = v[k]; }
  __syncthreads();

  // ---- fwd round 3 (n=16, q=1) + pointwise mult (registers) + inv round 1 ----
  #pragma unroll
  for (int k = 0; k < 16; ++k) v[k] = X[PHYS(16*t + k)];
  dft16<false>(v);
  #pragma unroll
  for (int j = 0; j < 8; ++j) {
    v[2*j]   = cmulf(v[2*j],   make_float2(kk[j].x, kk[j].y));
    v[2*j+1] = cmulf(v[2*j+1], make_float2(kk[j].z, kk[j].w));
  }
  dft16<true>(v);
  #pragma unroll
  for (int l = 0; l < 16; ++l) { int i = 16*t + l; X[PHYS(i)] = v[l]; }
  __syncthreads();

  // ---- inv round 2 (n=256, q=16): conj twiddle BEFORE inverse butterfly ----
  #pragma unroll
  for (int j = 0; j < 8; ++j) w[j] = twB[j];
  #pragma unroll
  for (int k = 0; k < 16; ++k) { int i = i0 + 16*k; v[k] = X[PHYS(i)]; }
  apply_tab_conj(v, w);
  dft16<true>(v);
  #pragma unroll
  for (int k = 0; k < 16; ++k) { int i = i0 + 16*k; X[PHYS(i)] = v[k]; }
  __syncthreads();

  // ---- inv round 3 (n=4096, q=256), fused with global store ----
  #pragma unroll
  for (int j = 0; j < 8; ++j) w[j] = twA[j];
  #pragma unroll
  for (int k = 0; k < 16; ++k) v[k] = X[PHYS(t + 256*k)];
  apply_tab_conj(v, w);
  dft16<true>(v);
  float* o1 = out + base;
  float* o2 = o1 + LEN;
  #pragma unroll
  for (int l = 0; l < 16; ++l) {
    o1[t + 256*l] = v[l].x;   // row 2b
    o2[t + 256*l] = v[l].y;   // row 2b+1
  }
}

extern "C" void kernel_launch(void* const* d_in, const int* in_sizes, int n_in,
                              void* d_out, int out_size, void* d_ws, size_t ws_size,
                              hipStream_t stream) {
  const float* x   = (const float*)d_in[0];
  const float* Lre = (const float*)d_in[1];
  const float* Lim = (const float*)d_in[2];
  const float* Pre = (const float*)d_in[3];
  const float* Pim = (const float*)d_in[4];
  const float* Bre = (const float*)d_in[5];
  const float* Bim = (const float*)d_in[6];
  const float* Cre = (const float*)d_in[7];
  const float* Cim = (const float*)d_in[8];
  float* out = (float*)d_out;

  float2* Kws     = (float2*)d_ws;       // 4096 float2 = 32 KB
  float2* keff_br = Kws + LEN;           // 32 KB
  float2* tw4096  = keff_br + LEN;       // 32 KB
  float2* tw256   = tw4096 + LEN;        // 2 KB

  s4_kernelA1<<<LEN, 64, 0, stream>>>(Lre, Lim, Pre, Pim, Bre, Bim, Cre, Cim, Kws);
  s4_kernelA2<<<LEN/256, 256, 0, stream>>>(Kws, keff_br);
  s4_kernelA3<<<LEN/256, 256, 0, stream>>>(tw4096, tw256);

  const int rows = out_size / LEN;   // 16*256 = 4096
  s4_fftconv<<<rows/2, 256, 0, stream>>>(x, keff_br, (const float4*)tw4096,
                                         (const float4*)tw256, out);
}